// Round 1
// baseline (704.880 us; speedup 1.0000x reference)
//
#include <hip/hip_runtime.h>
#include <math.h>

#define BN 1024
#define SN 64
#define DN 256
#define CHN 1024
#define GRP 16

__device__ __forceinline__ float gelu_exact(float x) {
    return 0.5f * x * (1.0f + erff(x * 0.70710678118654752440f));
}

// K1: scene logits + log_softmax + argmax. One block per sample b, 256 thr = 4 waves.
__global__ __launch_bounds__(256) void k_scene(
    const float* __restrict__ dt, const float* __restrict__ dr,
    const float* __restrict__ Wsc, const float* __restrict__ bsc,
    float* __restrict__ out_logd, int* __restrict__ max_idx)
{
    int b = blockIdx.x;
    int tid = threadIdx.x;
    int lane = tid & 63;
    int wave = tid >> 6;
    __shared__ float logits[SN];

    // each lane holds its 4-element slice of W_scene (t-part and rot-part)
    float4 wt = *(const float4*)&Wsc[4 * lane];
    float4 wr = *(const float4*)&Wsc[DN + 4 * lane];
    const float* pt = dt + (size_t)b * SN * DN;
    const float* pr = dr + (size_t)b * SN * DN;
    float bias0 = bsc[0];

    for (int s = wave; s < SN; s += 4) {
        float4 t4 = *(const float4*)&pt[s * DN + 4 * lane];
        float4 r4 = *(const float4*)&pr[s * DN + 4 * lane];
        float p = t4.x * wt.x + t4.y * wt.y + t4.z * wt.z + t4.w * wt.w
                + r4.x * wr.x + r4.y * wr.y + r4.z * wr.z + r4.w * wr.w;
        #pragma unroll
        for (int off = 32; off >= 1; off >>= 1) p += __shfl_xor(p, off);
        if (lane == 0) logits[s] = p + bias0;
    }
    __syncthreads();

    if (wave == 0) {
        float l = logits[lane];
        // butterfly max with first-index tie-break (matches jnp.argmax)
        float m = l; int idx = lane;
        #pragma unroll
        for (int off = 32; off >= 1; off >>= 1) {
            float om = __shfl_xor(m, off);
            int oidx = __shfl_xor(idx, off);
            if (om > m || (om == m && oidx < idx)) { m = om; idx = oidx; }
        }
        float e = expf(l - m);
        float ssum = e;
        #pragma unroll
        for (int off = 32; off >= 1; off >>= 1) ssum += __shfl_xor(ssum, off);
        float logZ = m + logf(ssum);
        out_logd[b * SN + lane] = l - logZ;
        if (lane == 0) max_idx[b] = idx;
    }
}

// K2: init pose output with the gathered output biases (atomics accumulate on top).
__global__ __launch_bounds__(256) void k_init_pose(
    const int* __restrict__ max_idx,
    const float* __restrict__ bt_o, const float* __restrict__ br_o,
    float* __restrict__ pose)
{
    int t = blockIdx.x * blockDim.x + threadIdx.x;
    if (t >= BN * 7) return;
    int b = t / 7, o = t % 7;
    int s = max_idx[b];
    pose[t] = (o < 3) ? bt_o[s * 3 + o] : br_o[s * 4 + (o - 3)];
}

// K3: bin samples by selected scene.
__global__ __launch_bounds__(256) void k_bin(
    const int* __restrict__ max_idx, int* __restrict__ counts, int* __restrict__ lists)
{
    int b = blockIdx.x * blockDim.x + threadIdx.x;
    if (b >= BN) return;
    int s = max_idx[b];
    int pos = atomicAdd(&counts[s], 1);
    lists[s * BN + pos] = b;
}

// K4: expert MLP heads, grouped by scene for weight reuse.
// grid: x = (group<<1)|h-half (128), y = scene (64), z = type (t=0, rot=1)
__global__ __launch_bounds__(256) void k_expert(
    const float* __restrict__ dt, const float* __restrict__ dr,
    const float* __restrict__ Wt_h, const float* __restrict__ bt_h, const float* __restrict__ Wt_o,
    const float* __restrict__ Wr_h, const float* __restrict__ br_h, const float* __restrict__ Wr_o,
    const int* __restrict__ counts, const int* __restrict__ lists,
    float* __restrict__ pose)
{
    int s = blockIdx.y;
    int z = blockIdx.z;
    int grp = blockIdx.x >> 1;
    int hh = blockIdx.x & 1;
    int cnt = counts[s];
    int base = grp * GRP;
    if (base >= cnt) return;
    int n = min(GRP, cnt - base);

    const float* Wh; const float* bh; const float* Wo; const float* descs; int no; int ob;
    if (z == 0) {
        Wh = Wt_h + (size_t)s * DN * CHN; bh = bt_h + s * CHN;
        Wo = Wt_o + (size_t)s * CHN * 3;  descs = dt; no = 3; ob = 0;
    } else {
        Wh = Wr_h + (size_t)s * DN * CHN; bh = br_h + s * CHN;
        Wo = Wr_o + (size_t)s * CHN * 4;  descs = dr; no = 4; ob = 3;
    }

    __shared__ float g[GRP][DN];
    __shared__ int bl[GRP];
    int tid = threadIdx.x;

    // stage gathered descriptors; pad unused rows with zeros (uniform compute)
    for (int i = 0; i < GRP; i++) {
        float v = 0.f;
        int bi = 0;
        if (i < n) {
            bi = lists[s * BN + base + i];
            v = descs[(size_t)bi * SN * DN + s * DN + tid];
        }
        g[i][tid] = v;
        if (tid == 0) bl[i] = bi;
    }
    __syncthreads();

    int h0 = hh * 512 + tid * 2;  // this thread's pair of hidden units
    float2 acc[GRP];
    #pragma unroll
    for (int i = 0; i < GRP; i++) acc[i] = make_float2(0.f, 0.f);

    for (int d = 0; d < DN; d += 4) {
        float2 wa = *(const float2*)&Wh[(size_t)d * CHN + h0];
        float2 wb = *(const float2*)&Wh[(size_t)(d + 1) * CHN + h0];
        float2 wc = *(const float2*)&Wh[(size_t)(d + 2) * CHN + h0];
        float2 wd = *(const float2*)&Wh[(size_t)(d + 3) * CHN + h0];
        #pragma unroll
        for (int i = 0; i < GRP; i++) {
            float4 gv = *(const float4*)&g[i][d];  // ds_read_b128, broadcast
            acc[i].x += gv.x * wa.x + gv.y * wb.x + gv.z * wc.x + gv.w * wd.x;
            acc[i].y += gv.x * wa.y + gv.y * wb.y + gv.z * wc.y + gv.w * wd.y;
        }
    }

    float b0 = bh[h0], b1 = bh[h0 + 1];
    int lane = tid & 63;
    for (int i = 0; i < n; i++) {
        float h0v = gelu_exact(acc[i].x + b0);
        float h1v = gelu_exact(acc[i].y + b1);
        for (int o = 0; o < no; o++) {
            float p = h0v * Wo[h0 * no + o] + h1v * Wo[(h0 + 1) * no + o];
            #pragma unroll
            for (int off = 32; off >= 1; off >>= 1) p += __shfl_down(p, off);
            if (lane == 0) atomicAdd(&pose[bl[i] * 7 + ob + o], p);
        }
    }
}

extern "C" void kernel_launch(void* const* d_in, const int* in_sizes, int n_in,
                              void* d_out, int out_size, void* d_ws, size_t ws_size,
                              hipStream_t stream) {
    const float* dt    = (const float*)d_in[0];
    const float* dr    = (const float*)d_in[1];
    const float* Wsc   = (const float*)d_in[2];
    const float* bsc   = (const float*)d_in[3];
    const float* Wt_h  = (const float*)d_in[4];
    const float* bt_h  = (const float*)d_in[5];
    const float* Wt_o  = (const float*)d_in[6];
    const float* bt_o  = (const float*)d_in[7];
    const float* Wr_h  = (const float*)d_in[8];
    const float* br_h  = (const float*)d_in[9];
    const float* Wr_o  = (const float*)d_in[10];
    const float* br_o  = (const float*)d_in[11];

    float* pose = (float*)d_out;                    // [B,7]
    float* logd = (float*)d_out + BN * 7;           // [B,S]

    int* max_idx = (int*)d_ws;                              // 4 KB
    int* counts  = (int*)((char*)d_ws + 4096);              // 256 B
    int* lists   = (int*)((char*)d_ws + 8192);              // 256 KB

    hipMemsetAsync(counts, 0, SN * sizeof(int), stream);

    k_scene<<<BN, 256, 0, stream>>>(dt, dr, Wsc, bsc, logd, max_idx);
    k_init_pose<<<(BN * 7 + 255) / 256, 256, 0, stream>>>(max_idx, bt_o, br_o, pose);
    k_bin<<<(BN + 255) / 256, 256, 0, stream>>>(max_idx, counts, lists);
    k_expert<<<dim3(128, SN, 2), 256, 0, stream>>>(
        dt, dr, Wt_h, bt_h, Wt_o, Wr_h, br_h, Wr_o, counts, lists, pose);
}

// Round 2
// 332.771 us; speedup vs baseline: 2.1182x; 2.1182x over previous
//
#include <hip/hip_runtime.h>
#include <math.h>

#define BN 1024
#define SN 64
#define DN 256
#define CHN 1024
#define GRP 16

__device__ __forceinline__ float gelu_exact(float x) {
    return 0.5f * x * (1.0f + erff(x * 0.70710678118654752440f));
}

// K1: scene logits + log_softmax + argmax. One block per sample b, 256 thr = 4 waves.
// Streaming loop is pure load+FMA (no cross-lane) so loads pipeline deeply;
// reduction deferred to one LDS pass.
__global__ __launch_bounds__(256) void k_scene(
    const float* __restrict__ dt, const float* __restrict__ dr,
    const float* __restrict__ Wsc, const float* __restrict__ bsc,
    float* __restrict__ out_logd, int* __restrict__ max_idx)
{
    int b = blockIdx.x;
    int tid = threadIdx.x;
    int lane = tid & 63;
    int wave = tid >> 6;
    __shared__ float part[SN][65];   // +1 pad: reduction read is 2-way (free)
    __shared__ float logits[SN];

    float4 wt = *(const float4*)&Wsc[4 * lane];
    float4 wr = *(const float4*)&Wsc[DN + 4 * lane];
    const float* pt = dt + (size_t)b * SN * DN + 4 * lane;
    const float* pr = dr + (size_t)b * SN * DN + 4 * lane;
    float bias0 = bsc[0];

    float p[16];
    #pragma unroll 4
    for (int k = 0; k < 16; k++) {
        int s = wave * 16 + k;          // each wave streams a contiguous 16KB chunk
        float4 t4 = *(const float4*)&pt[s * DN];
        float4 r4 = *(const float4*)&pr[s * DN];
        p[k] = t4.x * wt.x + t4.y * wt.y + t4.z * wt.z + t4.w * wt.w
             + r4.x * wr.x + r4.y * wr.y + r4.z * wr.z + r4.w * wr.w;
    }
    #pragma unroll
    for (int k = 0; k < 16; k++) part[wave * 16 + k][lane] = p[k];
    __syncthreads();

    // reduce 64 lane-partials per s: 4 threads per s, 16 each, then 2 shuffles
    {
        int s = tid >> 2, q = tid & 3;
        float sum = 0.f;
        #pragma unroll
        for (int j = 0; j < 16; j++) sum += part[s][q * 16 + j];
        sum += __shfl_xor(sum, 1);
        sum += __shfl_xor(sum, 2);
        if (q == 0) logits[s] = sum + bias0;
    }
    __syncthreads();

    if (wave == 0) {
        float l = logits[lane];
        float m = l; int idx = lane;
        #pragma unroll
        for (int off = 32; off >= 1; off >>= 1) {
            float om = __shfl_xor(m, off);
            int oidx = __shfl_xor(idx, off);
            if (om > m || (om == m && oidx < idx)) { m = om; idx = oidx; }
        }
        float e = expf(l - m);
        float ssum = e;
        #pragma unroll
        for (int off = 32; off >= 1; off >>= 1) ssum += __shfl_xor(ssum, off);
        float logZ = m + logf(ssum);
        out_logd[b * SN + lane] = l - logZ;
        if (lane == 0) max_idx[b] = idx;
    }
}

// K2: init pose output with the gathered output biases (atomics accumulate on top).
__global__ __launch_bounds__(256) void k_init_pose(
    const int* __restrict__ max_idx,
    const float* __restrict__ bt_o, const float* __restrict__ br_o,
    float* __restrict__ pose)
{
    int t = blockIdx.x * blockDim.x + threadIdx.x;
    if (t >= BN * 7) return;
    int b = t / 7, o = t % 7;
    int s = max_idx[b];
    pose[t] = (o < 3) ? bt_o[s * 3 + o] : br_o[s * 4 + (o - 3)];
}

// K3: bin samples by selected scene.
__global__ __launch_bounds__(256) void k_bin(
    const int* __restrict__ max_idx, int* __restrict__ counts, int* __restrict__ lists)
{
    int b = blockIdx.x * blockDim.x + threadIdx.x;
    if (b >= BN) return;
    int s = max_idx[b];
    int pos = atomicAdd(&counts[s], 1);
    lists[s * BN + pos] = b;
}

// K4: expert MLP heads, grouped by scene for weight reuse.
// grid.x = (scene<<2)|(type<<1)|hhalf  -> 256 dense ACTIVE blocks, spread on all CUs
// grid.y = sample group (y=0 always active; y>=1 sparse)
__global__ __launch_bounds__(256) void k_expert(
    const float* __restrict__ dt, const float* __restrict__ dr,
    const float* __restrict__ Wt_h, const float* __restrict__ bt_h, const float* __restrict__ Wt_o,
    const float* __restrict__ Wr_h, const float* __restrict__ br_h, const float* __restrict__ Wr_o,
    const int* __restrict__ counts, const int* __restrict__ lists,
    float* __restrict__ pose)
{
    int x = blockIdx.x;
    int s = x >> 2;
    int z = (x >> 1) & 1;
    int hh = x & 1;
    int grp = blockIdx.y;
    int cnt = counts[s];
    int base = grp * GRP;
    if (base >= cnt) return;
    int n = min(GRP, cnt - base);

    const float* Wh; const float* bh; const float* Wo; const float* descs; int no; int ob;
    if (z == 0) {
        Wh = Wt_h + (size_t)s * DN * CHN; bh = bt_h + s * CHN;
        Wo = Wt_o + (size_t)s * CHN * 3;  descs = dt; no = 3; ob = 0;
    } else {
        Wh = Wr_h + (size_t)s * DN * CHN; bh = br_h + s * CHN;
        Wo = Wr_o + (size_t)s * CHN * 4;  descs = dr; no = 4; ob = 3;
    }

    __shared__ float g[GRP][DN];
    __shared__ int bl[GRP];
    int tid = threadIdx.x;

    for (int i = 0; i < GRP; i++) {
        float v = 0.f;
        int bi = 0;
        if (i < n) {
            bi = lists[s * BN + base + i];
            v = descs[(size_t)bi * SN * DN + s * DN + tid];
        }
        g[i][tid] = v;
        if (tid == 0) bl[i] = bi;
    }
    __syncthreads();

    int h0 = hh * 512 + tid * 2;
    float2 acc[GRP];
    #pragma unroll
    for (int i = 0; i < GRP; i++) acc[i] = make_float2(0.f, 0.f);

    // 8-row unroll: 8 independent 8B weight loads in flight per thread per batch
    for (int d = 0; d < DN; d += 8) {
        float2 w[8];
        #pragma unroll
        for (int r = 0; r < 8; r++)
            w[r] = *(const float2*)&Wh[(size_t)(d + r) * CHN + h0];
        #pragma unroll
        for (int i = 0; i < GRP; i++) {
            float4 ga = *(const float4*)&g[i][d];      // broadcast ds_read_b128
            float4 gb = *(const float4*)&g[i][d + 4];
            acc[i].x += ga.x * w[0].x + ga.y * w[1].x + ga.z * w[2].x + ga.w * w[3].x
                      + gb.x * w[4].x + gb.y * w[5].x + gb.z * w[6].x + gb.w * w[7].x;
            acc[i].y += ga.x * w[0].y + ga.y * w[1].y + ga.z * w[2].y + ga.w * w[3].y
                      + gb.x * w[4].y + gb.y * w[5].y + gb.z * w[6].y + gb.w * w[7].y;
        }
    }

    float b0 = bh[h0], b1 = bh[h0 + 1];
    int lane = tid & 63;
    for (int i = 0; i < n; i++) {
        float h0v = gelu_exact(acc[i].x + b0);
        float h1v = gelu_exact(acc[i].y + b1);
        for (int o = 0; o < no; o++) {
            float p = h0v * Wo[h0 * no + o] + h1v * Wo[(h0 + 1) * no + o];
            #pragma unroll
            for (int off = 32; off >= 1; off >>= 1) p += __shfl_down(p, off);
            if (lane == 0) atomicAdd(&pose[bl[i] * 7 + ob + o], p);
        }
    }
}

extern "C" void kernel_launch(void* const* d_in, const int* in_sizes, int n_in,
                              void* d_out, int out_size, void* d_ws, size_t ws_size,
                              hipStream_t stream) {
    const float* dt    = (const float*)d_in[0];
    const float* dr    = (const float*)d_in[1];
    const float* Wsc   = (const float*)d_in[2];
    const float* bsc   = (const float*)d_in[3];
    const float* Wt_h  = (const float*)d_in[4];
    const float* bt_h  = (const float*)d_in[5];
    const float* Wt_o  = (const float*)d_in[6];
    const float* bt_o  = (const float*)d_in[7];
    const float* Wr_h  = (const float*)d_in[8];
    const float* br_h  = (const float*)d_in[9];
    const float* Wr_o  = (const float*)d_in[10];
    const float* br_o  = (const float*)d_in[11];

    float* pose = (float*)d_out;                    // [B,7]
    float* logd = (float*)d_out + BN * 7;           // [B,S]

    int* max_idx = (int*)d_ws;                              // 4 KB
    int* counts  = (int*)((char*)d_ws + 4096);              // 256 B
    int* lists   = (int*)((char*)d_ws + 8192);              // 256 KB

    hipMemsetAsync(counts, 0, SN * sizeof(int), stream);

    k_scene<<<BN, 256, 0, stream>>>(dt, dr, Wsc, bsc, logd, max_idx);
    k_init_pose<<<(BN * 7 + 255) / 256, 256, 0, stream>>>(max_idx, bt_o, br_o, pose);
    k_bin<<<(BN + 255) / 256, 256, 0, stream>>>(max_idx, counts, lists);
    k_expert<<<dim3(256, 64), 256, 0, stream>>>(
        dt, dr, Wt_h, bt_h, Wt_o, Wr_h, br_h, Wr_o, counts, lists, pose);
}